// Round 18
// baseline (593.449 us; speedup 1.0000x reference)
//
#include <hip/hip_runtime.h>
#include <hip/hip_bf16.h>
#include <cstdint>

#define B_  8
#define T_  16
#define HIN 640
#define WIN 480
#define HP  320
#define WP  240
#define HO  318
#define WO  238

typedef unsigned short u16;
typedef unsigned int   u32;
typedef __attribute__((ext_vector_type(8))) short bf16x8;
typedef __attribute__((ext_vector_type(4))) float f32x4;

#define TY    3
#define PITCH 16   // halfwords per pixel slot (32 B, contiguous -> global_load_lds OK)
#define NFRAG 25
#define NBY   106  // y-tiles (3 rows each: 318 exact)
#define NWG   (4 * NBY * B_)   // 3392

__device__ __forceinline__ u16 f2bf(float f) {          // RNE float->bf16 bits
    u32 u = __float_as_uint(f);
    return (u16)((u + 0x7fffu + ((u >> 16) & 1u)) >> 16);
}
__device__ __forceinline__ float bf2f(u16 u) {
    return __uint_as_float(((u32)u) << 16);
}
__device__ __forceinline__ float h2f(u16 u) {           // fp16 bits -> f32
    _Float16 h = __builtin_bit_cast(_Float16, u);
    return (float)h;
}
__device__ __forceinline__ u16 f2h(float f) {           // f32 -> fp16 bits
    _Float16 h = (_Float16)f;
    return __builtin_bit_cast(u16, h);
}
__device__ __forceinline__ float hsg(float v) {         // med3 clamp
    return __builtin_amdgcn_fmed3f(fmaf(v, 0.2f, 0.5f), 0.0f, 1.0f);
}
// tanh = 1 - 2/(e^{2x}+1)
__device__ __forceinline__ float tanh_fast(float x) {
    float e = __expf(2.0f * x);
    return 1.0f - __fdividef(2.0f, e + 1.0f);
}

// ---------------- MaxPool (1,2,2) -> bf16 ----------------
__global__ void pool_kernel(const float* __restrict__ in, u32* __restrict__ out) {
    int idx = blockIdx.x * 256 + threadIdx.x;
    const int total = B_ * T_ * HP * (WP / 2);
    if (idx >= total) return;
    int xp   = idx % (WP / 2);
    int rest = idx / (WP / 2);
    int y    = rest % HP;
    int bt   = rest / HP;
    const float* src = in + ((size_t)bt * HIN + 2 * y) * WIN + xp * 4;
    float4 a = *(const float4*)src;
    float4 b = *(const float4*)(src + WIN);
    float m0 = fmaxf(fmaxf(a.x, a.y), fmaxf(b.x, b.y));
    float m1 = fmaxf(fmaxf(a.z, a.w), fmaxf(b.z, b.w));
    out[((size_t)bt * HP + y) * (WP / 2) + xp] = (u32)f2bf(m0) | ((u32)f2bf(m1) << 16);
}

// ---------------- weight fragment pre-pack ----------------
__global__ void frag_build(const float* __restrict__ krec, const float* __restrict__ kin,
                           int4* __restrict__ fragbuf) {
    int idx = blockIdx.x * 256 + threadIdx.x;
    if (idx >= NFRAG * 64) return;
    int l = idx & 63, f = idx >> 6;
    int lo = (f >= 20);
    int q  = lo ? (f - 20) : (f >> 2);
    int nt = lo ? 2 : (f & 3);
    int n = nt * 16 + (l & 15), o = l >> 4;
    u16 u[8];
    #pragma unroll
    for (int j = 0; j < 8; ++j) {
        int k = q * 32 + o * 8 + j;
        float wv = 0.0f;
        if (k < 144) wv = krec[k * 64 + n];
        else if (k < 153) wv = kin[(k - 144) * 64 + n];
        u16 hi = f2bf(wv);
        u[j] = lo ? f2bf(wv - bf2f(hi)) : hi;
    }
    int4 v;
    v.x = (int)((u32)u[0] | ((u32)u[1] << 16));
    v.y = (int)((u32)u[2] | ((u32)u[3] << 16));
    v.z = (int)((u32)u[4] | ((u32)u[5] << 16));
    v.w = (int)((u32)u[6] | ((u32)u[7] << 16));
    fragbuf[f * 64 + l] = v;
}

// ---------------- fused ConvLSTM step (TY=3, 5 blocks/CU target) ----------------
// 1D grid 3392, XCD swizzle: b = wgid&7, by = wgid>>5 (of 106), bx = (wgid>>3)&3.
// c private block-slot: 12 fp16/thread as int4 + int2 (dense).
__global__ __launch_bounds__(256, 5)
void lstm_step(const u16* __restrict__ xpb, int t,
               const u16* __restrict__ hin,    // [b][y][x][16] bf16
               u16* __restrict__ hout,
               int4* __restrict__ cA, int2* __restrict__ cB,
               const int4* __restrict__ fragbuf,
               const float* __restrict__ bias, int lastT) {
    __shared__ __align__(16) u16 sh_h[5 * 66 * PITCH];   // 10,560 B
    __shared__ __align__(16) u16 sxf[2 * 256 * 8];       //  8,192 B (total 18,752)

    const int tid  = threadIdx.x;
    const int wgid = blockIdx.x;
    const int b    = wgid & 7;
    const int by   = wgid >> 5;
    const int bx   = (wgid >> 3) & 3;
    const int wv_ = tid >> 6;
    const int l   = tid & 63;
    const int y0  = by * TY;
    const int x0  = bx * 64;
    const int o   = l >> 4;
    const int ch  = l & 15;
    // interior: halo rows y0-1..y0+3 in [0,318), cols x0-1..x0+64 in [0,238),
    // x-pack rows to y0+5 < 320, cols to x0+65 < 240
    const bool fast = (t > 0) & (x0 >= 1) & (x0 <= 173) & (y0 >= 1) & (y0 <= 314);

    // stage h halo (5x66 px, 32 B/px contiguous)
    if (fast) {
        // 660 16-B units; unit u = (px = u>>1, half = u&1); dest = sh_h + u*16 B.
        const u16* hb = hin + (((size_t)b * HO + y0 - 1) * WO + x0 - 1) * 16;
        #pragma unroll
        for (int k = 0; k < 3; ++k) {
            const int unit = k * 256 + tid;
            if (unit < 660) {
                const int px = unit >> 1, half = unit & 1;
                const int hr = px / 66, hx = px - hr * 66;
                const u16* g = hb + ((size_t)hr * WO + hx) * 16 + half * 8;
                u16* lp = sh_h + (size_t)(k * 256 + wv_ * 64) * 8;   // wave-uniform base
                __builtin_amdgcn_global_load_lds(
                    (const __attribute__((address_space(1))) void*)g,
                    (__attribute__((address_space(3))) void*)lp, 16, 0, 0);
            }
        }
    } else {
        for (int i = tid; i < 5 * 66; i += 256) {
            int hr = i / 66, hx = i - hr * 66;
            int gy = y0 - 1 + hr, gx = x0 - 1 + hx;
            bool ok = (t > 0) && gy >= 0 && gy < HO && gx >= 0 && gx < WO;
            int4 v0 = make_int4(0, 0, 0, 0), v1 = v0;
            if (ok) {
                const int4* g = (const int4*)&hin[(((size_t)b * HO + gy) * WO + gx) * 16];
                v0 = g[0]; v1 = g[1];
            }
            u16* d = &sh_h[i * PITCH];
            *(int4*)d = v0; *(int4*)(d + 8) = v1;
        }
    }

    // ---- early c-load: dense int4 + int2 per thread ----
    int4 c01 = make_int4(0, 0, 0, 0);
    int2 c2  = make_int2(0, 0);
    if (t > 0) {
        c01 = cA[(size_t)wgid * 256 + tid];
        c2  = cB[(size_t)wgid * 256 + tid];
    }

    // pack x A-fragments (m = tid>>6; m=3 is a dummy slot, never read; in-bounds)
    {
        const int sxi = tid & 63, m = tid >> 6;
        const u16* xs = xpb + (size_t)(b * T_ + t) * HP * WP;
        u16 u[9];
        if (fast) {
            const u16* xr = xs + (size_t)(y0 + m) * WP + x0 + sxi;
            #pragma unroll
            for (int j = 0; j < 9; ++j) u[j] = xr[(j / 3) * WP + (j % 3)];
        } else {
            #pragma unroll
            for (int j = 0; j < 9; ++j) {
                int gy = y0 + m + j / 3, gx = x0 + sxi + j % 3;
                u[j] = (gy < HP && gx < WP) ? xs[(size_t)gy * WP + gx] : (u16)0;
            }
        }
        int4 p;
        p.x = (int)((u32)u[0] | ((u32)u[1] << 16));
        p.y = (int)((u32)u[2] | ((u32)u[3] << 16));
        p.z = (int)((u32)u[4] | ((u32)u[5] << 16));
        p.w = (int)((u32)u[6] | ((u32)u[7] << 16));
        *(int4*)&sxf[tid * 8] = p;
        *(int4*)&sxf[(256 + tid) * 8] = make_int4((int)(u32)u[8], 0, 0, 0);
    }
    __syncthreads();

    float bv[4];
    #pragma unroll
    for (int nt = 0; nt < 4; ++nt) bv[nt] = bias[nt * 16 + ch];

    f32x4 acc[TY][4];
    #pragma unroll
    for (int m = 0; m < TY; ++m)
        #pragma unroll
        for (int nt = 0; nt < 4; ++nt)
            acc[m][nt] = (f32x4){bv[nt], bv[nt], bv[nt], bv[nt]};

    const int ci0  = (o & 1) * 8;
    const bool hiH = (l >= 32);
    const int wx   = wv_ * 16 + (l & 15);
    const int4* fbl = fragbuf + l;

    // chunks 0..3 with depth-1 prefetch
    int4 nb0 = fbl[0 * 64], nb1 = fbl[1 * 64], nb2 = fbl[2 * 64], nb3 = fbl[3 * 64];
    #pragma unroll 1
    for (int q = 0; q < 4; ++q) {
        bf16x8 Bh0 = __builtin_bit_cast(bf16x8, nb0);
        bf16x8 Bh1 = __builtin_bit_cast(bf16x8, nb1);
        bf16x8 Bh2 = __builtin_bit_cast(bf16x8, nb2);
        bf16x8 Bh3 = __builtin_bit_cast(bf16x8, nb3);
        nb0 = fbl[((q + 1) * 4 + 0) * 64];
        nb1 = fbl[((q + 1) * 4 + 1) * 64];
        nb2 = fbl[((q + 1) * 4 + 2) * 64];
        nb3 = fbl[((q + 1) * 4 + 3) * 64];
        const int tap = 2 * q + (hiH ? 1 : 0);
        const int dy = tap / 3, dx = tap - 3 * dy;
        #pragma unroll
        for (int m = 0; m < TY; ++m) {
            bf16x8 Ah = *(const bf16x8*)&sh_h[((m + dy) * 66 + wx + dx) * PITCH + ci0];
            acc[m][0] = __builtin_amdgcn_mfma_f32_16x16x32_bf16(Ah, Bh0, acc[m][0], 0, 0, 0);
            acc[m][1] = __builtin_amdgcn_mfma_f32_16x16x32_bf16(Ah, Bh1, acc[m][1], 0, 0, 0);
            acc[m][2] = __builtin_amdgcn_mfma_f32_16x16x32_bf16(Ah, Bh2, acc[m][2], 0, 0, 0);
            acc[m][3] = __builtin_amdgcn_mfma_f32_16x16x32_bf16(Ah, Bh3, acc[m][3], 0, 0, 0);
        }
    }
    // chunk 4: o=0,1 rec tap8; o=2 x taps 0..7; o=3 x tap8
    {
        bf16x8 Bh0 = __builtin_bit_cast(bf16x8, nb0);
        bf16x8 Bh1 = __builtin_bit_cast(bf16x8, nb1);
        bf16x8 Bh2 = __builtin_bit_cast(bf16x8, nb2);
        bf16x8 Bh3 = __builtin_bit_cast(bf16x8, nb3);
        #pragma unroll
        for (int m = 0; m < TY; ++m) {
            bf16x8 Ah;
            if (!hiH) {
                Ah = *(const bf16x8*)&sh_h[((m + 2) * 66 + wx + 2) * PITCH + ci0];
            } else {
                const int slot = (o == 2 ? 0 : 256) + m * 64 + wx;
                Ah = *(const bf16x8*)&sxf[slot * 8];
            }
            acc[m][0] = __builtin_amdgcn_mfma_f32_16x16x32_bf16(Ah, Bh0, acc[m][0], 0, 0, 0);
            acc[m][1] = __builtin_amdgcn_mfma_f32_16x16x32_bf16(Ah, Bh1, acc[m][1], 0, 0, 0);
            acc[m][2] = __builtin_amdgcn_mfma_f32_16x16x32_bf16(Ah, Bh2, acc[m][2], 0, 0, 0);
            acc[m][3] = __builtin_amdgcn_mfma_f32_16x16x32_bf16(Ah, Bh3, acc[m][3], 0, 0, 0);
        }
    }

    // unpack c (compile-time indices)
    u16 cl[12];
    {
        u32 d;
        d = (u32)c01.x; cl[0] = (u16)d;  cl[1] = (u16)(d >> 16);
        d = (u32)c01.y; cl[2] = (u16)d;  cl[3] = (u16)(d >> 16);
        d = (u32)c01.z; cl[4] = (u16)d;  cl[5] = (u16)(d >> 16);
        d = (u32)c01.w; cl[6] = (u16)d;  cl[7] = (u16)(d >> 16);
        d = (u32)c2.x;  cl[8] = (u16)d;  cl[9] = (u16)(d >> 16);
        d = (u32)c2.y;  cl[10] = (u16)d; cl[11] = (u16)(d >> 16);
    }
    u16 cs[12];

    // gates + state update. C layout: col = ch, row = (l>>4)*4 + r (x offset).
    if (fast) {
        #pragma unroll
        for (int m = 0; m < TY; ++m) {
            size_t rowb = (((size_t)b * HO + y0 + m) * WO + x0 + wv_ * 16 + o * 4) * 16 + ch;
            #pragma unroll
            for (int r = 0; r < 4; ++r) {
                float co = h2f(cl[m * 4 + r]);
                float zi = acc[m][0][r], zf = acc[m][1][r], zc = acc[m][2][r], zo = acc[m][3][r];
                float cn = fmaf(hsg(zf), co, hsg(zi) * tanh_fast(zc));
                float hn = hsg(zo) * tanh_fast(cn);
                cs[m * 4 + r] = f2h(cn);
                hout[rowb + (size_t)r * 16] = f2bf(hn);
            }
        }
    } else {
        #pragma unroll
        for (int m = 0; m < TY; ++m) {
            const int y = y0 + m;
            #pragma unroll
            for (int r = 0; r < 4; ++r) {
                const int x = x0 + wv_ * 16 + o * 4 + r;
                float co = h2f(cl[m * 4 + r]);
                float zi = acc[m][0][r], zf = acc[m][1][r], zc = acc[m][2][r], zo = acc[m][3][r];
                float cn = fmaf(hsg(zf), co, hsg(zi) * tanh_fast(zc));
                float hn = hsg(zo) * tanh_fast(cn);
                cs[m * 4 + r] = f2h(cn);
                if (y < HO && x < WO)
                    hout[(((size_t)b * HO + y) * WO + x) * 16 + ch] = f2bf(hn);
            }
        }
    }
    if (!lastT) {
        int4 oo;
        oo.x = (int)((u32)cs[0] | ((u32)cs[1] << 16));
        oo.y = (int)((u32)cs[2] | ((u32)cs[3] << 16));
        oo.z = (int)((u32)cs[4] | ((u32)cs[5] << 16));
        oo.w = (int)((u32)cs[6] | ((u32)cs[7] << 16));
        int2 o2;
        o2.x = (int)((u32)cs[8]  | ((u32)cs[9]  << 16));
        o2.y = (int)((u32)cs[10] | ((u32)cs[11] << 16));
        cA[(size_t)wgid * 256 + tid] = oo;
        cB[(size_t)wgid * 256 + tid] = o2;
    }
}

// ---------------- dense ----------------
#define NPX    (HO * WO)
#define PCHUNK 512
#define NCHUNK ((NPX + PCHUNK - 1) / PCHUNK)   // 148

__device__ __forceinline__ float dot2(u32 a, float w0, float w1, float s) {
    s = fmaf(bf2f((u16)a), w0, s);
    return fmaf(bf2f((u16)(a >> 16)), w1, s);
}

__global__ void dense1(const u16* __restrict__ h, const float* __restrict__ w,
                       float* __restrict__ partial) {
    int b = blockIdx.y, tid = threadIdx.x;
    const u16* hb = h + (size_t)b * NPX * 16;
    float s = 0.0f;
    #pragma unroll
    for (int pp = 0; pp < 2; ++pp) {
        int px = blockIdx.x * PCHUNK + tid * 2 + pp;
        if (px < NPX) {
            const int4* g = (const int4*)&hb[(size_t)px * 16];
            int4 a0 = g[0], a1 = g[1];
            const float4* wp = (const float4*)&w[(size_t)px * 16];
            float4 w0 = wp[0], w1 = wp[1], w2 = wp[2], w3 = wp[3];
            s = dot2((u32)a0.x, w0.x, w0.y, s);
            s = dot2((u32)a0.y, w0.z, w0.w, s);
            s = dot2((u32)a0.z, w1.x, w1.y, s);
            s = dot2((u32)a0.w, w1.z, w1.w, s);
            s = dot2((u32)a1.x, w2.x, w2.y, s);
            s = dot2((u32)a1.y, w2.z, w2.w, s);
            s = dot2((u32)a1.z, w3.x, w3.y, s);
            s = dot2((u32)a1.w, w3.z, w3.w, s);
        }
    }
    #pragma unroll
    for (int of = 32; of > 0; of >>= 1) s += __shfl_down(s, of, 64);
    __shared__ float red[4];
    if ((tid & 63) == 0) red[tid >> 6] = s;
    __syncthreads();
    if (tid == 0) partial[b * NCHUNK + blockIdx.x] = red[0] + red[1] + red[2] + red[3];
}

__global__ void dense2(const float* __restrict__ partial, const float* __restrict__ db,
                       float* __restrict__ out) {
    int b = blockIdx.x, tid = threadIdx.x;
    float s = 0.0f;
    for (int i = tid; i < NCHUNK; i += 256) s += partial[b * NCHUNK + i];
    #pragma unroll
    for (int of = 32; of > 0; of >>= 1) s += __shfl_down(s, of, 64);
    __shared__ float red[4];
    if ((tid & 63) == 0) red[tid >> 6] = s;
    __syncthreads();
    if (tid == 0) out[b] = red[0] + red[1] + red[2] + red[3] + db[0];
}

extern "C" void kernel_launch(void* const* d_in, const int* in_sizes, int n_in,
                              void* d_out, int out_size, void* d_ws, size_t ws_size,
                              hipStream_t stream) {
    const float* inputs = (const float*)d_in[0];
    const float* kin    = (const float*)d_in[1];
    const float* krec   = (const float*)d_in[2];
    const float* bias   = (const float*)d_in[3];
    const float* dw     = (const float*)d_in[4];
    const float* db     = (const float*)d_in[5];
    float* out = (float*)d_out;

    const size_t XPN = (size_t)B_ * T_ * HP * WP;   // u16 pooled x
    const size_t HN  = (size_t)B_ * HO * WO * 16;   // u16 per h buffer

    u16*   xp   = (u16*)d_ws;
    u16*   h0   = xp + XPN;
    u16*   h1   = h0 + HN;
    int4*  cA   = (int4*)(h1 + HN);                 // NWG*256 int4
    int2*  cB   = (int2*)(cA + (size_t)NWG * 256);  // NWG*256 int2
    int4*  frag = (int4*)(cB + (size_t)NWG * 256);  // 25,600 B
    float* part = (float*)(frag + NFRAG * 64);

    {
        int total = B_ * T_ * HP * (WP / 2);
        pool_kernel<<<(total + 255) / 256, 256, 0, stream>>>(inputs, (u32*)xp);
    }
    frag_build<<<(NFRAG * 64 + 255) / 256, 256, 0, stream>>>(krec, kin, frag);

    for (int t = 0; t < T_; ++t) {
        const u16* hi = (t & 1) ? h1 : h0;
        u16*       ho = (t & 1) ? h0 : h1;
        lstm_step<<<NWG, 256, 0, stream>>>(xp, t, hi, ho, cA, cB, frag, bias, (t == T_ - 1));
    }
    // t=15 (odd) wrote h0
    dense1<<<dim3(NCHUNK, B_), 256, 0, stream>>>(h0, dw, part);
    dense2<<<B_, 256, 0, stream>>>(part, db, out);
}

// Round 19
// 518.920 us; speedup vs baseline: 1.1436x; 1.1436x over previous
//
#include <hip/hip_runtime.h>
#include <hip/hip_bf16.h>
#include <cstdint>

#define B_  8
#define T_  16
#define HIN 640
#define WIN 480
#define HP  320
#define WP  240
#define HO  318
#define WO  238

typedef unsigned short u16;
typedef unsigned int   u32;
typedef __attribute__((ext_vector_type(8))) short bf16x8;
typedef __attribute__((ext_vector_type(4))) float f32x4;

#define TY    4
#define PITCH 16   // halfwords per pixel slot (32 B, contiguous -> global_load_lds OK)
#define NFRAG 25
#define NBY   80   // y-tiles
#define NWG   (4 * NBY * B_)   // 2560
#define NPX   (HO * WO)

__device__ __forceinline__ u16 f2bf(float f) {          // RNE float->bf16 bits
    u32 u = __float_as_uint(f);
    return (u16)((u + 0x7fffu + ((u >> 16) & 1u)) >> 16);
}
__device__ __forceinline__ float bf2f(u16 u) {
    return __uint_as_float(((u32)u) << 16);
}
__device__ __forceinline__ float h2f(u16 u) {           // fp16 bits -> f32
    _Float16 h = __builtin_bit_cast(_Float16, u);
    return (float)h;
}
__device__ __forceinline__ u16 f2h(float f) {           // f32 -> fp16 bits
    _Float16 h = (_Float16)f;
    return __builtin_bit_cast(u16, h);
}
__device__ __forceinline__ float hsg(float v) {         // med3 clamp
    return __builtin_amdgcn_fmed3f(fmaf(v, 0.2f, 0.5f), 0.0f, 1.0f);
}
// tanh = 1 - 2/(e^{2x}+1)
__device__ __forceinline__ float tanh_fast(float x) {
    float e = __expf(2.0f * x);
    return 1.0f - __fdividef(2.0f, e + 1.0f);
}

// ---------------- MaxPool (1,2,2) -> bf16 ----------------
__global__ void pool_kernel(const float* __restrict__ in, u32* __restrict__ out) {
    int idx = blockIdx.x * 256 + threadIdx.x;
    const int total = B_ * T_ * HP * (WP / 2);
    if (idx >= total) return;
    int xp   = idx % (WP / 2);
    int rest = idx / (WP / 2);
    int y    = rest % HP;
    int bt   = rest / HP;
    const float* src = in + ((size_t)bt * HIN + 2 * y) * WIN + xp * 4;
    float4 a = *(const float4*)src;
    float4 b = *(const float4*)(src + WIN);
    float m0 = fmaxf(fmaxf(a.x, a.y), fmaxf(b.x, b.y));
    float m1 = fmaxf(fmaxf(a.z, a.w), fmaxf(b.z, b.w));
    out[((size_t)bt * HP + y) * (WP / 2) + xp] = (u32)f2bf(m0) | ((u32)f2bf(m1) << 16);
}

// ---------------- weight fragment pre-pack ----------------
__global__ void frag_build(const float* __restrict__ krec, const float* __restrict__ kin,
                           int4* __restrict__ fragbuf) {
    int idx = blockIdx.x * 256 + threadIdx.x;
    if (idx >= NFRAG * 64) return;
    int l = idx & 63, f = idx >> 6;
    int lo = (f >= 20);
    int q  = lo ? (f - 20) : (f >> 2);
    int nt = lo ? 2 : (f & 3);
    int n = nt * 16 + (l & 15), o = l >> 4;
    u16 u[8];
    #pragma unroll
    for (int j = 0; j < 8; ++j) {
        int k = q * 32 + o * 8 + j;
        float wv = 0.0f;
        if (k < 144) wv = krec[k * 64 + n];
        else if (k < 153) wv = kin[(k - 144) * 64 + n];
        u16 hi = f2bf(wv);
        u[j] = lo ? f2bf(wv - bf2f(hi)) : hi;
    }
    int4 v;
    v.x = (int)((u32)u[0] | ((u32)u[1] << 16));
    v.y = (int)((u32)u[2] | ((u32)u[3] << 16));
    v.z = (int)((u32)u[4] | ((u32)u[5] << 16));
    v.w = (int)((u32)u[6] | ((u32)u[7] << 16));
    fragbuf[f * 64 + l] = v;
}

// ---------------- fused ConvLSTM step ----------------
// 1D grid 2560, XCD swizzle: b = wgid&7 (each XCD owns one batch), by = wgid>>5,
// bx = (wgid>>3)&3. c in private block-slot layout [wgid][tid][16] fp16.
// At t==T-1: h is not stored; the dense dot (h . w) partial is computed per block
// (deterministic fixed-order reduction) into part[wgid].
__global__ __launch_bounds__(256, 4)
void lstm_step(const u16* __restrict__ xpb, int t,
               const u16* __restrict__ hin,    // [b][y][x][16] bf16
               u16* __restrict__ hout,
               u16* __restrict__ cbuf,         // [wgid][256][16] fp16
               const int4* __restrict__ fragbuf,
               const float* __restrict__ bias,
               const float* __restrict__ dw,   // dense weights (flat, per-batch shared)
               float* __restrict__ part,       // [NWG] partials (written at lastT)
               int lastT) {
    __shared__ __align__(16) u16 sh_h[6 * 66 * PITCH];   // 12,672 B
    __shared__ __align__(16) u16 sxf[2 * 256 * 8];       //  8,192 B
    __shared__ float red[4];

    const int tid  = threadIdx.x;
    const int wgid = blockIdx.x;
    const int b    = wgid & 7;
    const int by   = wgid >> 5;
    const int bx   = (wgid >> 3) & 3;
    const int wv_ = tid >> 6;
    const int l   = tid & 63;
    const int y0  = by * TY;
    const int x0  = bx * 64;
    const int o   = l >> 4;
    const int ch  = l & 15;
    const bool fast = (t > 0) & (x0 >= 1) & (x0 <= 173) & (y0 >= 1) & (y0 <= 313);

    // stage h halo (6x66 px, 32 B/px contiguous)
    if (fast) {
        const u16* hb = hin + (((size_t)b * HO + y0 - 1) * WO + x0 - 1) * 16;
        #pragma unroll
        for (int k = 0; k < 4; ++k) {
            const int unit = k * 256 + tid;
            if (unit < 792) {
                const int px = unit >> 1, half = unit & 1;
                const int hr = px / 66, hx = px - hr * 66;
                const u16* g = hb + ((size_t)hr * WO + hx) * 16 + half * 8;
                u16* lp = sh_h + (size_t)(k * 256 + wv_ * 64) * 8;   // wave-uniform base
                __builtin_amdgcn_global_load_lds(
                    (const __attribute__((address_space(1))) void*)g,
                    (__attribute__((address_space(3))) void*)lp, 16, 0, 0);
            }
        }
    } else {
        for (int i = tid; i < 6 * 66; i += 256) {
            int hr = i / 66, hx = i - hr * 66;
            int gy = y0 - 1 + hr, gx = x0 - 1 + hx;
            bool ok = (t > 0) && gy >= 0 && gy < HO && gx >= 0 && gx < WO;
            int4 v0 = make_int4(0, 0, 0, 0), v1 = v0;
            if (ok) {
                const int4* g = (const int4*)&hin[(((size_t)b * HO + gy) * WO + gx) * 16];
                v0 = g[0]; v1 = g[1];
            }
            u16* d = &sh_h[i * PITCH];
            *(int4*)d = v0; *(int4*)(d + 8) = v1;
        }
    }

    // ---- early c-load: 2 dense int4 per thread, in flight through MFMA section ----
    int4 c01 = make_int4(0, 0, 0, 0), c23 = c01;
    if (t > 0) {
        const int4* cp = (const int4*)cbuf + ((size_t)wgid * 256 + tid) * 2;
        c01 = cp[0]; c23 = cp[1];
    }

    // pack x A-fragments
    {
        const int sxi = tid & 63, m = tid >> 6;
        const u16* xs = xpb + (size_t)(b * T_ + t) * HP * WP;
        u16 u[9];
        if (fast) {
            const u16* xr = xs + (size_t)(y0 + m) * WP + x0 + sxi;
            #pragma unroll
            for (int j = 0; j < 9; ++j) u[j] = xr[(j / 3) * WP + (j % 3)];
        } else {
            #pragma unroll
            for (int j = 0; j < 9; ++j) {
                int gy = y0 + m + j / 3, gx = x0 + sxi + j % 3;
                u[j] = (gy < HP && gx < WP) ? xs[(size_t)gy * WP + gx] : (u16)0;
            }
        }
        int4 p;
        p.x = (int)((u32)u[0] | ((u32)u[1] << 16));
        p.y = (int)((u32)u[2] | ((u32)u[3] << 16));
        p.z = (int)((u32)u[4] | ((u32)u[5] << 16));
        p.w = (int)((u32)u[6] | ((u32)u[7] << 16));
        *(int4*)&sxf[tid * 8] = p;
        *(int4*)&sxf[(256 + tid) * 8] = make_int4((int)(u32)u[8], 0, 0, 0);
    }
    __syncthreads();

    float bv[4];
    #pragma unroll
    for (int nt = 0; nt < 4; ++nt) bv[nt] = bias[nt * 16 + ch];

    f32x4 acc[TY][4];
    #pragma unroll
    for (int m = 0; m < TY; ++m)
        #pragma unroll
        for (int nt = 0; nt < 4; ++nt)
            acc[m][nt] = (f32x4){bv[nt], bv[nt], bv[nt], bv[nt]};

    const int ci0  = (o & 1) * 8;
    const bool hiH = (l >= 32);
    const int wx   = wv_ * 16 + (l & 15);
    const int4* fbl = fragbuf + l;

    // chunks 0..3 with depth-1 prefetch
    int4 nb0 = fbl[0 * 64], nb1 = fbl[1 * 64], nb2 = fbl[2 * 64], nb3 = fbl[3 * 64];
    #pragma unroll 1
    for (int q = 0; q < 4; ++q) {
        bf16x8 Bh0 = __builtin_bit_cast(bf16x8, nb0);
        bf16x8 Bh1 = __builtin_bit_cast(bf16x8, nb1);
        bf16x8 Bh2 = __builtin_bit_cast(bf16x8, nb2);
        bf16x8 Bh3 = __builtin_bit_cast(bf16x8, nb3);
        nb0 = fbl[((q + 1) * 4 + 0) * 64];
        nb1 = fbl[((q + 1) * 4 + 1) * 64];
        nb2 = fbl[((q + 1) * 4 + 2) * 64];
        nb3 = fbl[((q + 1) * 4 + 3) * 64];
        const int tap = 2 * q + (hiH ? 1 : 0);
        const int dy = tap / 3, dx = tap - 3 * dy;
        #pragma unroll
        for (int m = 0; m < TY; ++m) {
            bf16x8 Ah = *(const bf16x8*)&sh_h[((m + dy) * 66 + wx + dx) * PITCH + ci0];
            acc[m][0] = __builtin_amdgcn_mfma_f32_16x16x32_bf16(Ah, Bh0, acc[m][0], 0, 0, 0);
            acc[m][1] = __builtin_amdgcn_mfma_f32_16x16x32_bf16(Ah, Bh1, acc[m][1], 0, 0, 0);
            acc[m][2] = __builtin_amdgcn_mfma_f32_16x16x32_bf16(Ah, Bh2, acc[m][2], 0, 0, 0);
            acc[m][3] = __builtin_amdgcn_mfma_f32_16x16x32_bf16(Ah, Bh3, acc[m][3], 0, 0, 0);
        }
    }
    // chunk 4
    {
        bf16x8 Bh0 = __builtin_bit_cast(bf16x8, nb0);
        bf16x8 Bh1 = __builtin_bit_cast(bf16x8, nb1);
        bf16x8 Bh2 = __builtin_bit_cast(bf16x8, nb2);
        bf16x8 Bh3 = __builtin_bit_cast(bf16x8, nb3);
        #pragma unroll
        for (int m = 0; m < TY; ++m) {
            bf16x8 Ah;
            if (!hiH) {
                Ah = *(const bf16x8*)&sh_h[((m + 2) * 66 + wx + 2) * PITCH + ci0];
            } else {
                const int slot = (o == 2 ? 0 : 256) + m * 64 + wx;
                Ah = *(const bf16x8*)&sxf[slot * 8];
            }
            acc[m][0] = __builtin_amdgcn_mfma_f32_16x16x32_bf16(Ah, Bh0, acc[m][0], 0, 0, 0);
            acc[m][1] = __builtin_amdgcn_mfma_f32_16x16x32_bf16(Ah, Bh1, acc[m][1], 0, 0, 0);
            acc[m][2] = __builtin_amdgcn_mfma_f32_16x16x32_bf16(Ah, Bh2, acc[m][2], 0, 0, 0);
            acc[m][3] = __builtin_amdgcn_mfma_f32_16x16x32_bf16(Ah, Bh3, acc[m][3], 0, 0, 0);
        }
    }

    // unpack c (all indices compile-time)
    u16 cl[16];
    {
        u32 d;
        d = (u32)c01.x; cl[0] = (u16)d;  cl[1] = (u16)(d >> 16);
        d = (u32)c01.y; cl[2] = (u16)d;  cl[3] = (u16)(d >> 16);
        d = (u32)c01.z; cl[4] = (u16)d;  cl[5] = (u16)(d >> 16);
        d = (u32)c01.w; cl[6] = (u16)d;  cl[7] = (u16)(d >> 16);
        d = (u32)c23.x; cl[8] = (u16)d;  cl[9] = (u16)(d >> 16);
        d = (u32)c23.y; cl[10] = (u16)d; cl[11] = (u16)(d >> 16);
        d = (u32)c23.z; cl[12] = (u16)d; cl[13] = (u16)(d >> 16);
        d = (u32)c23.w; cl[14] = (u16)d; cl[15] = (u16)(d >> 16);
    }
    u16 cs[16];
    float dsum = 0.0f;
    const size_t bbase = (size_t)b * NPX * 16;

    // gates + state update. C layout: col = ch, row = (l>>4)*4 + r (x offset).
    if (fast) {
        #pragma unroll
        for (int m = 0; m < TY; ++m) {
            size_t rowb = (((size_t)b * HO + y0 + m) * WO + x0 + wv_ * 16 + o * 4) * 16 + ch;
            #pragma unroll
            for (int r = 0; r < 4; ++r) {
                size_t gc = rowb + (size_t)r * 16;
                float co = h2f(cl[m * 4 + r]);
                float zi = acc[m][0][r], zf = acc[m][1][r], zc = acc[m][2][r], zo = acc[m][3][r];
                float cn = fmaf(hsg(zf), co, hsg(zi) * tanh_fast(zc));
                float hn = hsg(zo) * tanh_fast(cn);
                cs[m * 4 + r] = f2h(cn);
                if (!lastT) hout[gc] = f2bf(hn);
                else        dsum = fmaf(bf2f(f2bf(hn)), dw[gc - bbase], dsum);
            }
        }
    } else {
        #pragma unroll
        for (int m = 0; m < TY; ++m) {
            const int y = y0 + m;
            #pragma unroll
            for (int r = 0; r < 4; ++r) {
                const int x = x0 + wv_ * 16 + o * 4 + r;
                float co = h2f(cl[m * 4 + r]);
                float zi = acc[m][0][r], zf = acc[m][1][r], zc = acc[m][2][r], zo = acc[m][3][r];
                float cn = fmaf(hsg(zf), co, hsg(zi) * tanh_fast(zc));
                float hn = hsg(zo) * tanh_fast(cn);
                cs[m * 4 + r] = f2h(cn);
                if (y < HO && x < WO) {
                    size_t gc = (((size_t)b * HO + y) * WO + x) * 16 + ch;
                    if (!lastT) hout[gc] = f2bf(hn);
                    else        dsum = fmaf(bf2f(f2bf(hn)), dw[gc - bbase], dsum);
                }
            }
        }
    }
    if (!lastT) {
        int4 o01, o23;
        o01.x = (int)((u32)cs[0]  | ((u32)cs[1]  << 16));
        o01.y = (int)((u32)cs[2]  | ((u32)cs[3]  << 16));
        o01.z = (int)((u32)cs[4]  | ((u32)cs[5]  << 16));
        o01.w = (int)((u32)cs[6]  | ((u32)cs[7]  << 16));
        o23.x = (int)((u32)cs[8]  | ((u32)cs[9]  << 16));
        o23.y = (int)((u32)cs[10] | ((u32)cs[11] << 16));
        o23.z = (int)((u32)cs[12] | ((u32)cs[13] << 16));
        o23.w = (int)((u32)cs[14] | ((u32)cs[15] << 16));
        int4* cp = (int4*)cbuf + ((size_t)wgid * 256 + tid) * 2;
        cp[0] = o01; cp[1] = o23;
    } else {
        // deterministic block reduction of the dense partial
        #pragma unroll
        for (int of = 32; of > 0; of >>= 1) dsum += __shfl_down(dsum, of, 64);
        if ((tid & 63) == 0) red[tid >> 6] = dsum;
        __syncthreads();
        if (tid == 0) part[wgid] = red[0] + red[1] + red[2] + red[3];
    }
}

// ---------------- dense final reduce (fixed order, deterministic) ----------------
__global__ void dense2(const float* __restrict__ part, const float* __restrict__ db,
                       float* __restrict__ out) {
    int b = blockIdx.x, tid = threadIdx.x;
    float s = 0.0f;
    for (int k = tid; k < NBY * 4; k += 256) s += part[(size_t)k * 8 + b];
    #pragma unroll
    for (int of = 32; of > 0; of >>= 1) s += __shfl_down(s, of, 64);
    __shared__ float red[4];
    if ((tid & 63) == 0) red[tid >> 6] = s;
    __syncthreads();
    if (tid == 0) out[b] = red[0] + red[1] + red[2] + red[3] + db[0];
}

extern "C" void kernel_launch(void* const* d_in, const int* in_sizes, int n_in,
                              void* d_out, int out_size, void* d_ws, size_t ws_size,
                              hipStream_t stream) {
    const float* inputs = (const float*)d_in[0];
    const float* kin    = (const float*)d_in[1];
    const float* krec   = (const float*)d_in[2];
    const float* bias   = (const float*)d_in[3];
    const float* dw     = (const float*)d_in[4];
    const float* db     = (const float*)d_in[5];
    float* out = (float*)d_out;

    const size_t XPN = (size_t)B_ * T_ * HP * WP;   // u16 pooled x
    const size_t HN  = (size_t)B_ * HO * WO * 16;   // u16 per h buffer
    const size_t CN  = (size_t)NWG * 256 * 16;      // u16 c (block-slot layout)

    u16*   xp   = (u16*)d_ws;
    u16*   h0   = xp + XPN;
    u16*   h1   = h0 + HN;
    u16*   cbuf = h1 + HN;
    int4*  frag = (int4*)(cbuf + CN);               // 25,600 B
    float* part = (float*)(frag + NFRAG * 64);      // NWG floats

    {
        int total = B_ * T_ * HP * (WP / 2);
        pool_kernel<<<(total + 255) / 256, 256, 0, stream>>>(inputs, (u32*)xp);
    }
    frag_build<<<(NFRAG * 64 + 255) / 256, 256, 0, stream>>>(krec, kin, frag);

    for (int t = 0; t < T_; ++t) {
        const u16* hi = (t & 1) ? h1 : h0;
        u16*       ho = (t & 1) ? h0 : h1;
        lstm_step<<<NWG, 256, 0, stream>>>(xp, t, hi, ho, cbuf, frag, bias,
                                           dw, part, (t == T_ - 1));
    }
    dense2<<<B_, 256, 0, stream>>>(part, db, out);
}